// Round 12
// baseline (238.616 us; speedup 1.0000x reference)
//
#include <hip/hip_runtime.h>

#define NNODES 50000
#define NEDGES 800000
#define HIDDIM 256
#define NB_SCAN 196   // ceil(NNODES/256)

constexpr float kAlpha = 0.1f;
constexpr float kBnEps = 1e-5f;
constexpr float kBeta  = 0.40546510810816438198f;   // log(1.5)

typedef __attribute__((ext_vector_type(8))) short  bf16x8;   // 8 bf16 in 4 VGPRs
typedef __attribute__((ext_vector_type(4))) float  f32x4;

typedef __attribute__((address_space(1))) const unsigned int gu32;  // global
typedef __attribute__((address_space(3))) unsigned int       lu32;  // LDS

static __device__ __forceinline__ unsigned short f2bf(float f) {
  unsigned u = __float_as_uint(f);
  u = (u + 0x7FFFu + ((u >> 16) & 1u)) >> 16;      // RTNE
  return (unsigned short)u;
}
static __device__ __forceinline__ float bf2f(unsigned short h) {
  return __uint_as_float(((unsigned)h) << 16);
}

// ---------------------------------------------------------------------------
// prep (blocks 0..511): weight transposes + zero BN stats
// hist (blocks 512..): degree histogram over edge dst (int4 vectorized)
// deg[] and scan-status[] zeroed by a preceding hipMemsetAsync.
// ---------------------------------------------------------------------------
__global__ __launch_bounds__(256) void prep_hist_k(const float* __restrict__ W_pre,
                                                   const float* __restrict__ W_op,
                                                   unsigned short* __restrict__ wpre_t,
                                                   unsigned short* __restrict__ wop_t,
                                                   float* __restrict__ colsum,
                                                   float* __restrict__ colsumsq,
                                                   const int* __restrict__ ei,
                                                   int* __restrict__ deg) {
  const int b = blockIdx.x, t = threadIdx.x;
  if (b < 256) {
    wpre_t[b * 256 + t] = f2bf(W_pre[t * 256 + b]);
    if (b == 0) { colsum[t] = 0.f; colsumsq[t] = 0.f; }
  } else if (b < 512) {
    int n = b - 256;
    wop_t[n * 256 + t] = f2bf(W_op[t * 256 + n]);
  } else {
    const int4* dst4 = (const int4*)(ei + NEDGES);
    const int n4 = NEDGES / 4;
    const int nb = gridDim.x - 512;
    for (int i = (b - 512) * 256 + t; i < n4; i += nb * 256) {
      int4 d = dst4[i];
      atomicAdd(&deg[d.x], 1);
      atomicAdd(&deg[d.y], 1);
      atomicAdd(&deg[d.z], 1);
      atomicAdd(&deg[d.w], 1);
    }
  }
}

// ---------------------------------------------------------------------------
// Single-dispatch exclusive scan, decoupled lookback with WAVE-PARALLEL
// 64-wide windows (lane i polls predecessor base-i; ballot finds nearest
// inclusive-prefix; one shfl reduction per window; <=3 windows for 196
// blocks). All 196 blocks co-resident on 256 CUs -> spin is safe.
// status: 0=invalid, 1=aggregate posted, 2=inclusive posted.
// ---------------------------------------------------------------------------
__global__ __launch_bounds__(256) void scan_k(const int* __restrict__ deg,
                                              int* __restrict__ rowptr,
                                              int* __restrict__ cursor,
                                              int* __restrict__ aggv,
                                              int* __restrict__ inclv,
                                              int* __restrict__ status) {
  __shared__ int sh[256];
  __shared__ int s_prefix;
  const int b = blockIdx.x, t = threadIdx.x;
  const int idx = b * 256 + t;
  int v = (idx < NNODES) ? deg[idx] : 0;
  sh[t] = v;
  __syncthreads();
  for (int off = 1; off < 256; off <<= 1) {
    int x = (t >= off) ? sh[t - off] : 0;
    __syncthreads();
    sh[t] += x;
    __syncthreads();
  }
  const int total = sh[255];
  if (t == 0) {
    __hip_atomic_store(&aggv[b], total, __ATOMIC_RELAXED, __HIP_MEMORY_SCOPE_AGENT);
    __hip_atomic_store(&status[b], 1, __ATOMIC_RELEASE, __HIP_MEMORY_SCOPE_AGENT);
    if (b == 0) {
      __hip_atomic_store(&inclv[0], total, __ATOMIC_RELAXED, __HIP_MEMORY_SCOPE_AGENT);
      __hip_atomic_store(&status[0], 2, __ATOMIC_RELEASE, __HIP_MEMORY_SCOPE_AGENT);
      s_prefix = 0;
    }
  }
  if (b > 0 && t < 64) {
    const int lane = t;
    int prefix = 0;
    for (int base = b - 1; base >= 0; base -= 64) {
      int p = base - lane;
      bool active = (p >= 0);
      int st = 0, val = 0;
      if (active) {
        do {
          st = __hip_atomic_load(&status[p], __ATOMIC_ACQUIRE, __HIP_MEMORY_SCOPE_AGENT);
        } while (st == 0);
        val = (st == 2)
            ? __hip_atomic_load(&inclv[p], __ATOMIC_RELAXED, __HIP_MEMORY_SCOPE_AGENT)
            : __hip_atomic_load(&aggv[p],  __ATOMIC_RELAXED, __HIP_MEMORY_SCOPE_AGENT);
      }
      unsigned long long m = __ballot(active && (st == 2));
      int cut = m ? (__ffsll((long long)m) - 1) : 64;     // nearest inclusive lane
      int contrib = (active && lane <= cut) ? val : 0;
#pragma unroll
      for (int o = 1; o < 64; o <<= 1) contrib += __shfl_xor(contrib, o, 64);
      prefix += contrib;
      if (cut < 64) break;                                // found inclusive prefix
    }
    if (t == 0) {
      __hip_atomic_store(&inclv[b], prefix + total, __ATOMIC_RELAXED, __HIP_MEMORY_SCOPE_AGENT);
      __hip_atomic_store(&status[b], 2, __ATOMIC_RELEASE, __HIP_MEMORY_SCOPE_AGENT);
      s_prefix = prefix;
      if (b == NB_SCAN - 1) rowptr[NNODES] = prefix + total;   // = NEDGES
    }
  }
  __syncthreads();
  if (idx < NNODES) {
    int base = (b == 0) ? 0 : s_prefix;
    int excl = base + sh[t] - v;
    rowptr[idx] = excl;
    cursor[idx] = excl;
  }
  if (b == 0 && t == 0) rowptr[0] = 0;
}

// ---------------------------------------------------------------------------
// CSR fill (standalone): bucket src ids into absolute slots
// ---------------------------------------------------------------------------
__global__ __launch_bounds__(256) void fill_k(const int* __restrict__ ei,
                                              int* __restrict__ cursor,
                                              int* __restrict__ esrc) {
  const int4* src4 = (const int4*)ei;
  const int4* dst4 = (const int4*)(ei + NEDGES);
  const int n4 = NEDGES / 4;
  int stride = gridDim.x * blockDim.x;
  for (int i = blockIdx.x * blockDim.x + threadIdx.x; i < n4; i += stride) {
    int4 s = src4[i];
    int4 d = dst4[i];
    esrc[atomicAdd(&cursor[d.x], 1)] = s.x;
    esrc[atomicAdd(&cursor[d.y], 1)] = s.y;
    esrc[atomicAdd(&cursor[d.z], 1)] = s.z;
    esrc[atomicAdd(&cursor[d.w], 1)] = s.w;
  }
}

// ---------------------------------------------------------------------------
// bf16 MFMA GEMM: C = A[M,256] @ B[256,256], Bt transposed [n][k].
// 64x256 tile (782 blocks -> ~3/CU, one residency round), BK=64, 4 K-steps,
// 4 waves (2x2: 32 rows x 128 cols each), XOR-swizzled LDS, global_load_lds.
// MODE 0: A fp32 (reg-staged + converted); C bf16 raw + column sum/sumsq
// MODE 1: A bf16 (global_load_lds); C fp32 = relu((1-beta)*S + beta*(A@B))
// ---------------------------------------------------------------------------
template<int MODE>
__global__ __launch_bounds__(256) void gemm_bf16_k(
    const void* __restrict__ Ain,
    const unsigned short* __restrict__ Bt,   // [256][256] bf16, Bt[n][k]
    void* __restrict__ Cout,                 // MODE0: bf16; MODE1: float
    const unsigned short* __restrict__ S,    // MODE1: residual bf16
    float* __restrict__ colsum,
    float* __restrict__ colsumsq,
    int M) {
  __shared__ unsigned short Al[64 * 64];     // 8 KB, row stride 128 B
  __shared__ unsigned short Bl[256 * 64];    // 32 KB
  __shared__ float cs[4][128], cq[4][128];   // MODE0 column-stat reduction

  const int t    = threadIdx.x;
  const int lane = t & 63;
  const int wid  = t >> 6;
  const int wr   = wid >> 1;                 // wave row (0/1): rows wr*32..+31
  const int wc   = wid & 1;                  // wave col (0/1): cols wc*128..+127
  const int row0 = blockIdx.x * 64;

  f32x4 acc[2][8] = {};

  // MODE0 reg-staging: thread -> (row t&63, k-seg t>>6 of 16 elems)
  const int srow = t & 63;
  const int sseg = t >> 6;                   // 0..3
  const int arow = row0 + srow;
  const bool aok = arow < M;
  const int swzA = (srow & 7) << 4;

  // global_load_lds decomposition: 1 issue = 1024 B = 8 rows x 128 B
  const int lrow = lane >> 3;                // 0..7
  const int lchk = lane & 7;                 // 16B chunk within row
  const int lsw  = (lchk * 16) ^ ((lrow & 7) << 4);   // inverse-swizzled src off

  for (int ks = 0; ks < 4; ++ks) {
    if (ks) __syncthreads();
    const int k0 = ks * 64;
    // ---- stage A ----
    if (MODE == 0) {
      const float* src = (const float*)Ain + (size_t)arow * 256 + k0 + sseg * 16;
      bf16x8 v0 = {}, v1 = {};
      if (aok) {
        float4 p0 = *(const float4*)(src + 0);
        float4 p1 = *(const float4*)(src + 4);
        float4 p2 = *(const float4*)(src + 8);
        float4 p3 = *(const float4*)(src + 12);
        v0[0] = (short)f2bf(p0.x); v0[1] = (short)f2bf(p0.y);
        v0[2] = (short)f2bf(p0.z); v0[3] = (short)f2bf(p0.w);
        v0[4] = (short)f2bf(p1.x); v0[5] = (short)f2bf(p1.y);
        v0[6] = (short)f2bf(p1.z); v0[7] = (short)f2bf(p1.w);
        v1[0] = (short)f2bf(p2.x); v1[1] = (short)f2bf(p2.y);
        v1[2] = (short)f2bf(p2.z); v1[3] = (short)f2bf(p2.w);
        v1[4] = (short)f2bf(p3.x); v1[5] = (short)f2bf(p3.y);
        v1[6] = (short)f2bf(p3.z); v1[7] = (short)f2bf(p3.w);
      }
      char* base = (char*)Al + srow * 128;
      *(bf16x8*)(base + ((sseg * 32 +  0) ^ swzA)) = v0;
      *(bf16x8*)(base + ((sseg * 32 + 16) ^ swzA)) = v1;
    } else {
      // 8 issues total, 2 per wave
#pragma unroll
      for (int c = 0; c < 2; ++c) {
        int chunk = wid * 2 + c;             // 0..7
        int row = chunk * 8 + lrow;          // 0..63 (OOB rows read ws garbage; masked at store)
        const char* g = (const char*)Ain + ((size_t)(row0 + row) * 256 + k0) * 2 + lsw;
        char* l = (char*)Al + chunk * 1024 + lane * 16;
        __builtin_amdgcn_global_load_lds((gu32*)g, (lu32*)l, 16, 0, 0);
      }
    }
    // ---- stage B: 32 issues, 8 per wave ----
#pragma unroll
    for (int c = 0; c < 8; ++c) {
      int chunk = wid * 8 + c;               // 0..31
      int row = chunk * 8 + lrow;            // 0..255
      const char* g = (const char*)Bt + ((size_t)row * 256 + k0) * 2 + lsw;
      char* l = (char*)Bl + chunk * 1024 + lane * 16;
      __builtin_amdgcn_global_load_lds((gu32*)g, (lu32*)l, 16, 0, 0);
    }
    __syncthreads();

    // ---- compute: 2 k-slices x 16 MFMA ----
#pragma unroll
    for (int kk = 0; kk < 2; ++kk) {
      const int koff = kk * 64 + ((lane >> 4) * 16);
      bf16x8 af[2], bfr[8];
#pragma unroll
      for (int m = 0; m < 2; ++m) {
        int row = wr * 32 + m * 16 + (lane & 15);
        af[m] = *(const bf16x8*)((char*)Al + row * 128 + (koff ^ ((row & 7) << 4)));
      }
#pragma unroll
      for (int n = 0; n < 8; ++n) {
        int nr = wc * 128 + n * 16 + (lane & 15);
        bfr[n] = *(const bf16x8*)((char*)Bl + nr * 128 + (koff ^ ((nr & 7) << 4)));
      }
#pragma unroll
      for (int m = 0; m < 2; ++m)
#pragma unroll
        for (int n = 0; n < 8; ++n)
          acc[m][n] = __builtin_amdgcn_mfma_f32_16x16x32_bf16(af[m], bfr[n], acc[m][n], 0, 0, 0);
    }
  }

  // ---- MODE 0: column sum / sumsq (OOB rows contributed exact zeros) ----
  if (MODE == 0) {
#pragma unroll
    for (int n = 0; n < 8; ++n) {
      float s = 0.f, q = 0.f;
#pragma unroll
      for (int m = 0; m < 2; ++m)
#pragma unroll
        for (int r = 0; r < 4; ++r) {
          float v = acc[m][n][r];
          s += v; q += v * v;
        }
      s += __shfl_xor(s, 16); s += __shfl_xor(s, 32);
      q += __shfl_xor(q, 16); q += __shfl_xor(q, 32);
      if (lane < 16) { cs[wid][n * 16 + lane] = s; cq[wid][n * 16 + lane] = q; }
    }
    __syncthreads();
    {
      int wcg = t >> 7;                      // column half (0/1) -> waves wcg, wcg+2
      int lc  = t & 127;
      atomicAdd(&colsum[t],   cs[wcg][lc] + cs[wcg + 2][lc]);
      atomicAdd(&colsumsq[t], cq[wcg][lc] + cq[wcg + 2][lc]);
    }
  }

  // ---- store (C/D layout: col=lane&15, row=(lane>>4)*4+r) ----
#pragma unroll
  for (int m = 0; m < 2; ++m) {
    int rbase = row0 + wr * 32 + m * 16 + (lane >> 4) * 4;
#pragma unroll
    for (int r = 0; r < 4; ++r) {
      int row = rbase + r;
      if (row < M) {
#pragma unroll
        for (int n = 0; n < 8; ++n) {
          int col = wc * 128 + n * 16 + (lane & 15);
          float v = acc[m][n][r];
          if (MODE == 0) {
            ((unsigned short*)Cout)[(size_t)row * 256 + col] = f2bf(v);
          } else {
            float s = bf2f(S[(size_t)row * 256 + col]);
            ((float*)Cout)[(size_t)row * 256 + col] =
                fmaxf((1.f - kBeta) * s + kBeta * v, 0.f);
          }
        }
      }
    }
  }
}

// ---------------------------------------------------------------------------
// Gather-sum per destination node with fused BN-finalize + BN/ReLU + GCNII
// support mix. Half-wave (32 lanes x 16B) per node; shfl-broadcast indices;
// gathers unrolled x4; x0 loads / supp stores non-temporal.
// ---------------------------------------------------------------------------
__global__ __launch_bounds__(256) void agg_bn_support_k(
    const unsigned short* __restrict__ hb,
    const int* __restrict__ rowptr,
    const int* __restrict__ esrc,
    const float* __restrict__ x0,
    const float* __restrict__ colsum,
    const float* __restrict__ colsumsq,
    const float* __restrict__ gamma,
    const float* __restrict__ beta_bn,
    unsigned short* __restrict__ supp_bf) {
  __shared__ float s_sc[256], s_sh[256];
  {
    int j = threadIdx.x;
    float inv_n = 1.0f / (float)NNODES;
    float mu  = colsum[j] * inv_n;
    float var = colsumsq[j] * inv_n - mu * mu;
    float rstd = rsqrtf(var + kBnEps);
    float g = gamma[j] * rstd;
    s_sc[j] = g;
    s_sh[j] = beta_bn[j] - mu * g;
  }
  __syncthreads();

  const int hw   = threadIdx.x >> 5;
  const int lane = threadIdx.x & 31;
  const int d    = blockIdx.x * 8 + hw;
  const int off  = lane * 8;

  float sc[8], sh[8];
  *(float4*)&sc[0] = *(const float4*)(s_sc + off);
  *(float4*)&sc[4] = *(const float4*)(s_sc + off + 4);
  *(float4*)&sh[0] = *(const float4*)(s_sh + off);
  *(float4*)&sh[4] = *(const float4*)(s_sh + off + 4);

  const int beg = rowptr[d];
  const int end = rowptr[d + 1];
  float acc[8] = {0.f, 0.f, 0.f, 0.f, 0.f, 0.f, 0.f, 0.f};

  for (int bb = beg; bb < end; bb += 32) {
    int cnt = end - bb; if (cnt > 32) cnt = 32;
    int myi = esrc[bb + ((lane < cnt) ? lane : 0)];
    int u = 0;
    for (; u + 3 < cnt; u += 4) {
      int s0 = __shfl(myi, u, 32),     s1 = __shfl(myi, u + 1, 32);
      int s2 = __shfl(myi, u + 2, 32), s3 = __shfl(myi, u + 3, 32);
      bf16x8 v0 = *(const bf16x8*)(hb + (size_t)s0 * HIDDIM + off);
      bf16x8 v1 = *(const bf16x8*)(hb + (size_t)s1 * HIDDIM + off);
      bf16x8 v2 = *(const bf16x8*)(hb + (size_t)s2 * HIDDIM + off);
      bf16x8 v3 = *(const bf16x8*)(hb + (size_t)s3 * HIDDIM + off);
#pragma unroll
      for (int j = 0; j < 8; ++j) {
        acc[j] += fmaxf(fmaf(bf2f((unsigned short)v0[j]), sc[j], sh[j]), 0.f)
                + fmaxf(fmaf(bf2f((unsigned short)v1[j]), sc[j], sh[j]), 0.f)
                + fmaxf(fmaf(bf2f((unsigned short)v2[j]), sc[j], sh[j]), 0.f)
                + fmaxf(fmaf(bf2f((unsigned short)v3[j]), sc[j], sh[j]), 0.f);
      }
    }
    for (; u < cnt; ++u) {
      int s0 = __shfl(myi, u, 32);
      bf16x8 v0 = *(const bf16x8*)(hb + (size_t)s0 * HIDDIM + off);
#pragma unroll
      for (int j = 0; j < 8; ++j)
        acc[j] += fmaxf(fmaf(bf2f((unsigned short)v0[j]), sc[j], sh[j]), 0.f);
    }
  }

  bf16x8 vd = *(const bf16x8*)(hb + (size_t)d * HIDDIM + off);
  f32x4 xa = __builtin_nontemporal_load((const f32x4*)(x0 + (size_t)d * HIDDIM + off));
  f32x4 xb = __builtin_nontemporal_load((const f32x4*)(x0 + (size_t)d * HIDDIM + off + 4));
  float xs[8] = {xa.x, xa.y, xa.z, xa.w, xb.x, xb.y, xb.z, xb.w};
  bf16x8 o;
#pragma unroll
  for (int j = 0; j < 8; ++j) {
    float hv = fmaxf(fmaf(bf2f((unsigned short)vd[j]), sc[j], sh[j]), 0.f);
    o[j] = (short)f2bf((1.f - kAlpha) * (hv + acc[j]) + kAlpha * xs[j]);
  }
  __builtin_nontemporal_store(o, (bf16x8*)(supp_bf + (size_t)d * HIDDIM + off));
}

// ---------------------------------------------------------------------------
extern "C" void kernel_launch(void* const* d_in, const int* in_sizes, int n_in,
                              void* d_out, int out_size, void* d_ws, size_t ws_size,
                              hipStream_t stream) {
  // inputs: s0, s1, x_0, W_pre, gamma, beta_bn, W_op, edge_index, drop_prob, training
  const float* s1    = (const float*)d_in[1];
  const float* x0    = (const float*)d_in[2];
  const float* W_pre = (const float*)d_in[3];
  const float* gamma = (const float*)d_in[4];
  const float* betab = (const float*)d_in[5];
  const float* W_op  = (const float*)d_in[6];
  const int*   ei    = (const int*)d_in[7];
  float* out = (float*)d_out;

  const size_t NH = (size_t)NNODES * HIDDIM;            // 12.8M elements
  unsigned short* hbf   = (unsigned short*)d_ws;        // 25.6 MB (raw bf16 h)
  unsigned short* supbf = hbf + NH;                     // 25.6 MB
  float* colsum   = (float*)(supbf + NH);               // 256
  float* colsumsq = colsum + HIDDIM;
  unsigned short* wpre_t = (unsigned short*)(colsumsq + HIDDIM);  // 128 KB
  unsigned short* wop_t  = wpre_t + 65536;              // 128 KB
  int* deg      = (int*)(wop_t + 65536);                // 50000
  int* status   = deg + NNODES;                         // 256 (memset with deg)
  int* cursor   = status + 256;                         // 50000
  int* rowptr   = cursor + NNODES;                      // 50001
  int* esrc     = rowptr + (NNODES + 1);                // 800000
  int* aggv     = esrc + NEDGES;                        // 256
  int* inclv    = aggv + 256;                           // 256

  // zero deg + scan status in one memset
  hipMemsetAsync(deg, 0, (NNODES + 256) * sizeof(int), stream);

  // weight transposes + BN-stat zero + degree histogram (fused)
  prep_hist_k<<<1024, 256, 0, stream>>>(W_pre, W_op, wpre_t, wop_t,
                                        colsum, colsumsq, ei, deg);

  // single-dispatch scan with wave-parallel lookback (rowptr + cursor seed)
  scan_k<<<NB_SCAN, 256, 0, stream>>>(deg, rowptr, cursor, aggv, inclv, status);

  // CSR fill
  fill_k<<<1024, 256, 0, stream>>>(ei, cursor, esrc);

  // GEMM1 (fp32 A converted in staging) -> raw bf16 h + BN stats
  const int gx = (NNODES + 63) / 64;
  gemm_bf16_k<0><<<gx, 256, 0, stream>>>(s1, wpre_t, hbf, nullptr, colsum, colsumsq, NNODES);

  // gather + fused BN-finalize/BN/ReLU + support mix
  agg_bn_support_k<<<(NNODES + 7) / 8, 256, 0, stream>>>(hbf, rowptr, esrc, x0,
                                                         colsum, colsumsq, gamma, betab,
                                                         supbf);

  // GEMM2 + GCNII epilogue
  gemm_bf16_k<1><<<gx, 256, 0, stream>>>(supbf, wop_t, out, supbf, nullptr, nullptr, NNODES);
}

// Round 13
// 218.721 us; speedup vs baseline: 1.0910x; 1.0910x over previous
//
#include <hip/hip_runtime.h>

#define NNODES 50000
#define NEDGES 800000
#define HIDDIM 256
#define NB_SCAN 196   // ceil(NNODES/256)
#define NCHUNK  1563  // ceil(NNODES/32)
#define GEMMB   256   // persistent GEMM blocks (1 per CU)

constexpr float kAlpha = 0.1f;
constexpr float kBnEps = 1e-5f;
constexpr float kBeta  = 0.40546510810816438198f;   // log(1.5)

typedef __attribute__((ext_vector_type(8))) short  bf16x8;   // 8 bf16 in 4 VGPRs
typedef __attribute__((ext_vector_type(4))) float  f32x4;

typedef __attribute__((address_space(1))) const unsigned int gu32;  // global
typedef __attribute__((address_space(3))) unsigned int       lu32;  // LDS

static __device__ __forceinline__ unsigned short f2bf(float f) {
  unsigned u = __float_as_uint(f);
  u = (u + 0x7FFFu + ((u >> 16) & 1u)) >> 16;      // RTNE
  return (unsigned short)u;
}
static __device__ __forceinline__ float bf2f(unsigned short h) {
  return __uint_as_float(((unsigned)h) << 16);
}

// ---------------------------------------------------------------------------
// prep: weight transposes (fp32 [k][n] -> bf16 [n][k]) + zero BN stats + deg
// ---------------------------------------------------------------------------
__global__ __launch_bounds__(256) void prep_k(const float* __restrict__ W_pre,
                                              const float* __restrict__ W_op,
                                              unsigned short* __restrict__ wpre_t,
                                              unsigned short* __restrict__ wop_t,
                                              float* __restrict__ colsum,
                                              float* __restrict__ colsumsq,
                                              int* __restrict__ deg) {
  int b = blockIdx.x, t = threadIdx.x;
  if (b < 256) {
    wpre_t[b * 256 + t] = f2bf(W_pre[t * 256 + b]);
    if (b == 0) { colsum[t] = 0.f; colsumsq[t] = 0.f; }
  } else {
    int n = b - 256;
    wop_t[n * 256 + t] = f2bf(W_op[t * 256 + n]);
  }
  if (b < NB_SCAN) {
    int idx = b * 256 + t;
    if (idx < NNODES) deg[idx] = 0;
  }
}

// ---------------------------------------------------------------------------
// CSR build: degree histogram -> 3-phase parallel scan -> bucket src ids
// (round-10 proven versions)
// ---------------------------------------------------------------------------
__global__ __launch_bounds__(256) void hist_k(const int* __restrict__ ei,
                                              int* __restrict__ deg) {
  const int4* dst4 = (const int4*)(ei + NEDGES);
  const int n4 = NEDGES / 4;
  int stride = gridDim.x * blockDim.x;
  for (int i = blockIdx.x * blockDim.x + threadIdx.x; i < n4; i += stride) {
    int4 d = dst4[i];
    atomicAdd(&deg[d.x], 1);
    atomicAdd(&deg[d.y], 1);
    atomicAdd(&deg[d.z], 1);
    atomicAdd(&deg[d.w], 1);
  }
}

__global__ __launch_bounds__(256) void scanA_k(const int* __restrict__ deg,
                                               int* __restrict__ rowptr,
                                               int* __restrict__ blocksum) {
  __shared__ int sh[256];
  const int t = threadIdx.x;
  const int idx = blockIdx.x * 256 + t;
  int v = (idx < NNODES) ? deg[idx] : 0;
  sh[t] = v;
  __syncthreads();
  for (int off = 1; off < 256; off <<= 1) {
    int x = (t >= off) ? sh[t - off] : 0;
    __syncthreads();
    sh[t] += x;
    __syncthreads();
  }
  if (idx < NNODES) rowptr[idx] = sh[t] - v;      // exclusive within block
  if (t == 255) blocksum[blockIdx.x] = sh[255];
}

__global__ __launch_bounds__(256) void scanB_k(const int* __restrict__ blocksum,
                                               int* __restrict__ blockoff,
                                               int* __restrict__ rowptr) {
  __shared__ int sh[256];
  const int t = threadIdx.x;
  int v = (t < NB_SCAN) ? blocksum[t] : 0;
  sh[t] = v;
  __syncthreads();
  for (int off = 1; off < 256; off <<= 1) {
    int x = (t >= off) ? sh[t - off] : 0;
    __syncthreads();
    sh[t] += x;
    __syncthreads();
  }
  blockoff[t] = sh[t] - v;                        // exclusive block offset
  if (t == 255) rowptr[NNODES] = sh[255];         // grand total (=NEDGES)
}

__global__ __launch_bounds__(256) void scanC_k(int* __restrict__ rowptr,
                                               const int* __restrict__ blockoff,
                                               int* __restrict__ cursor) {
  const int idx = blockIdx.x * 256 + threadIdx.x;
  if (idx < NNODES) {
    int rp = rowptr[idx] + blockoff[blockIdx.x];
    rowptr[idx] = rp;
    cursor[idx] = rp;
  }
}

__global__ __launch_bounds__(256) void fill_k(const int* __restrict__ ei,
                                              int* __restrict__ cursor,
                                              int* __restrict__ esrc) {
  const int4* src4 = (const int4*)ei;
  const int4* dst4 = (const int4*)(ei + NEDGES);
  const int n4 = NEDGES / 4;
  int stride = gridDim.x * blockDim.x;
  for (int i = blockIdx.x * blockDim.x + threadIdx.x; i < n4; i += stride) {
    int4 s = src4[i];
    int4 d = dst4[i];
    esrc[atomicAdd(&cursor[d.x], 1)] = s.x;
    esrc[atomicAdd(&cursor[d.y], 1)] = s.y;
    esrc[atomicAdd(&cursor[d.z], 1)] = s.z;
    esrc[atomicAdd(&cursor[d.w], 1)] = s.w;
  }
}

// ---------------------------------------------------------------------------
// PERSISTENT bf16 MFMA GEMM: C = A[M,256] @ B[256,256], Bt transposed [n][k].
// 256 blocks (1/CU), 512 threads (8 waves as 2 row-groups x 4 col-groups).
// B (128 KB) lives in LDS for the whole kernel; A streams through a 2x16KB
// double buffer in 32-row chunks; one barrier per chunk; full K=256 per MFMA
// pass (32 MFMA/wave/chunk). XOR swizzle ((row&7)<<4) on 512-B LDS rows;
// global_load_lds sources are inverse-swizzled (rule #21).
// MODE 0: A fp32 (reg-staged+converted); C bf16 + col stats (reg-accumulated,
//         one atomicAdd/col/block at end).
// MODE 1: A bf16 via global_load_lds; S residual == A read back from LDS;
//         C fp32 = relu((1-beta)*S + beta*(A@B)).
// ---------------------------------------------------------------------------
template<int MODE>
__global__ __launch_bounds__(512) void gemm_persist_k(
    const void* __restrict__ Ain,
    const unsigned short* __restrict__ Bt,   // [256][256] bf16, Bt[n][k]
    void* __restrict__ Cout,                 // MODE0: bf16; MODE1: float
    float* __restrict__ colsum,
    float* __restrict__ colsumsq,
    int M) {
  __shared__ __align__(16) unsigned short Bl[256 * 256];   // 128 KB, 512 B rows
  __shared__ __align__(16) unsigned short Al[2][32 * 256]; // 2 x 16 KB

  const int t    = threadIdx.x;          // 0..511
  const int lane = t & 63;
  const int wid  = t >> 6;               // 0..7
  const int wr   = wid >> 2;             // row group 0/1 (16 rows each)
  const int wc   = wid & 3;              // col group 0..3 (64 cols each)

  // ---- B preload: 128 issues x 1 KB (2 rows each), 16 per wave ----
  {
    const int lrow = lane >> 5;          // 0..1
    const int lchk = lane & 31;          // 16B chunk in 512-B row
#pragma unroll
    for (int c = 0; c < 16; ++c) {
      int issue = wid * 16 + c;          // 0..127
      int row = issue * 2 + lrow;        // 0..255
      int srcoff = (lchk * 16) ^ ((row & 7) << 4);
      const char* g = (const char*)Bt + (size_t)row * 512 + srcoff;
      char* l = (char*)Bl + issue * 1024 + lane * 16;
      __builtin_amdgcn_global_load_lds((gu32*)g, (lu32*)l, 16, 0, 0);
    }
  }

  float spart[4] = {0.f, 0.f, 0.f, 0.f};
  float qpart[4] = {0.f, 0.f, 0.f, 0.f};

  auto stageA = [&](int buf, int chunk) {
    const int r0 = chunk * 32;
    if (MODE == 0) {
      // 512 threads -> (row 0..31, seg 0..15 of 16 fp32)
      const int row = t >> 4;
      const int seg = t & 15;
      const int arow = r0 + row;
      const float* src = (const float*)Ain + (size_t)arow * 256 + seg * 16;
      bf16x8 v0 = {}, v1 = {};
      if (arow < M) {
        float4 p0 = *(const float4*)(src + 0);
        float4 p1 = *(const float4*)(src + 4);
        float4 p2 = *(const float4*)(src + 8);
        float4 p3 = *(const float4*)(src + 12);
        v0[0] = (short)f2bf(p0.x); v0[1] = (short)f2bf(p0.y);
        v0[2] = (short)f2bf(p0.z); v0[3] = (short)f2bf(p0.w);
        v0[4] = (short)f2bf(p1.x); v0[5] = (short)f2bf(p1.y);
        v0[6] = (short)f2bf(p1.z); v0[7] = (short)f2bf(p1.w);
        v1[0] = (short)f2bf(p2.x); v1[1] = (short)f2bf(p2.y);
        v1[2] = (short)f2bf(p2.z); v1[3] = (short)f2bf(p2.w);
        v1[4] = (short)f2bf(p3.x); v1[5] = (short)f2bf(p3.y);
        v1[6] = (short)f2bf(p3.z); v1[7] = (short)f2bf(p3.w);
      }
      char* base = (char*)&Al[buf][0] + row * 512;
      const int sw = (row & 7) << 4;
      *(bf16x8*)(base + ((seg * 32 +  0) ^ sw)) = v0;
      *(bf16x8*)(base + ((seg * 32 + 16) ^ sw)) = v1;
    } else {
      // 16 issues x 1 KB (2 rows each), 2 per wave
      const int lrow = lane >> 5;
      const int lchk = lane & 31;
#pragma unroll
      for (int c = 0; c < 2; ++c) {
        int issue = wid * 2 + c;         // 0..15
        int row = issue * 2 + lrow;      // 0..31
        int srcoff = (lchk * 16) ^ ((row & 7) << 4);
        const char* g = (const char*)Ain + (size_t)(r0 + row) * 512 + srcoff;
        char* l = (char*)&Al[buf][0] + issue * 1024 + lane * 16;
        __builtin_amdgcn_global_load_lds((gu32*)g, (lu32*)l, 16, 0, 0);
      }
    }
  };

  stageA(0, blockIdx.x);
  __syncthreads();                       // B + first A ready

  int nc = 0;
  for (int c = blockIdx.x; c < NCHUNK; c += GEMMB, ++nc) {
    const int cur = nc & 1;
    const int cn = c + GEMMB;
    if (cn < NCHUNK) stageA(cur ^ 1, cn);   // next chunk flies under MFMA

    // ---- compute: full K=256, 8 k-slices x 4 n = 32 MFMA ----
    f32x4 acc[4] = {};
    const int arow_f = wr * 16 + (lane & 15);
    const int asw = (arow_f & 7) << 4;
#pragma unroll
    for (int ks = 0; ks < 8; ++ks) {
      const int koff = ks * 64 + ((lane >> 4) * 16);
      bf16x8 af = *(const bf16x8*)((char*)&Al[cur][0] + arow_f * 512 + (koff ^ asw));
#pragma unroll
      for (int n = 0; n < 4; ++n) {
        int nr = wc * 64 + n * 16 + (lane & 15);
        bf16x8 bfr = *(const bf16x8*)((char*)Bl + (size_t)nr * 512 + (koff ^ ((nr & 7) << 4)));
        acc[n] = __builtin_amdgcn_mfma_f32_16x16x32_bf16(af, bfr, acc[n], 0, 0, 0);
      }
    }

    // ---- epilogue (C/D layout: col=lane&15, row=(lane>>4)*4+r) ----
    if (MODE == 0) {
      unsigned short* hC = (unsigned short*)Cout;
#pragma unroll
      for (int n = 0; n < 4; ++n) {
        int col = wc * 64 + n * 16 + (lane & 15);
        float s = 0.f, q = 0.f;
#pragma unroll
        for (int r = 0; r < 4; ++r) {
          int row = c * 32 + wr * 16 + (lane >> 4) * 4 + r;
          float v = acc[n][r];
          s += v; q += v * v;
          if (row < M) hC[(size_t)row * 256 + col] = f2bf(v);
        }
        spart[n] += s; qpart[n] += q;
      }
    } else {
      float* oC = (float*)Cout;
#pragma unroll
      for (int n = 0; n < 4; ++n) {
        int col = wc * 64 + n * 16 + (lane & 15);
#pragma unroll
        for (int r = 0; r < 4; ++r) {
          int rl = wr * 16 + (lane >> 4) * 4 + r;
          int row = c * 32 + rl;
          if (row < M) {
            // residual S == A row, still resident in Al[cur]
            unsigned short sv = *(const unsigned short*)
                ((char*)&Al[cur][0] + rl * 512 + ((col * 2) ^ ((rl & 7) << 4)));
            oC[(size_t)row * 256 + col] =
                fmaxf((1.f - kBeta) * bf2f(sv) + kBeta * acc[n][r], 0.f);
          }
        }
      }
    }
    __syncthreads();   // drains next-chunk loads; protects Al[cur] for rewrite
  }

  // ---- MODE 0: fold register col-stats into global (1 atomic/col/block) ----
  if (MODE == 0) {
#pragma unroll
    for (int n = 0; n < 4; ++n) {
      float s = spart[n], q = qpart[n];
      s += __shfl_xor(s, 16); s += __shfl_xor(s, 32);
      q += __shfl_xor(q, 16); q += __shfl_xor(q, 32);
      if (lane < 16) {
        int col = wc * 64 + n * 16 + lane;
        atomicAdd(&colsum[col], s);
        atomicAdd(&colsumsq[col], q);
      }
    }
  }
}

// ---------------------------------------------------------------------------
// Gather-sum per destination node with fused BN-finalize + BN/ReLU + GCNII
// support mix (round-10 proven version).
// ---------------------------------------------------------------------------
__global__ __launch_bounds__(256) void agg_bn_support_k(
    const unsigned short* __restrict__ hb,
    const int* __restrict__ rowptr,
    const int* __restrict__ esrc,
    const float* __restrict__ x0,
    const float* __restrict__ colsum,
    const float* __restrict__ colsumsq,
    const float* __restrict__ gamma,
    const float* __restrict__ beta_bn,
    unsigned short* __restrict__ supp_bf) {
  __shared__ float s_sc[256], s_sh[256];
  {
    int j = threadIdx.x;
    float inv_n = 1.0f / (float)NNODES;
    float mu  = colsum[j] * inv_n;
    float var = colsumsq[j] * inv_n - mu * mu;
    float rstd = rsqrtf(var + kBnEps);
    float g = gamma[j] * rstd;
    s_sc[j] = g;
    s_sh[j] = beta_bn[j] - mu * g;
  }
  __syncthreads();

  const int hw   = threadIdx.x >> 5;
  const int lane = threadIdx.x & 31;
  const int d    = blockIdx.x * 8 + hw;
  const int off  = lane * 8;

  float sc[8], sh[8];
  *(float4*)&sc[0] = *(const float4*)(s_sc + off);
  *(float4*)&sc[4] = *(const float4*)(s_sc + off + 4);
  *(float4*)&sh[0] = *(const float4*)(s_sh + off);
  *(float4*)&sh[4] = *(const float4*)(s_sh + off + 4);

  const int beg = rowptr[d];
  const int end = rowptr[d + 1];
  float acc[8] = {0.f, 0.f, 0.f, 0.f, 0.f, 0.f, 0.f, 0.f};

  for (int bb = beg; bb < end; bb += 32) {
    int cnt = end - bb; if (cnt > 32) cnt = 32;
    int myi = esrc[bb + ((lane < cnt) ? lane : 0)];
    int u = 0;
    for (; u + 3 < cnt; u += 4) {
      int s0 = __shfl(myi, u, 32),     s1 = __shfl(myi, u + 1, 32);
      int s2 = __shfl(myi, u + 2, 32), s3 = __shfl(myi, u + 3, 32);
      bf16x8 v0 = *(const bf16x8*)(hb + (size_t)s0 * HIDDIM + off);
      bf16x8 v1 = *(const bf16x8*)(hb + (size_t)s1 * HIDDIM + off);
      bf16x8 v2 = *(const bf16x8*)(hb + (size_t)s2 * HIDDIM + off);
      bf16x8 v3 = *(const bf16x8*)(hb + (size_t)s3 * HIDDIM + off);
#pragma unroll
      for (int j = 0; j < 8; ++j) {
        acc[j] += fmaxf(fmaf(bf2f((unsigned short)v0[j]), sc[j], sh[j]), 0.f)
                + fmaxf(fmaf(bf2f((unsigned short)v1[j]), sc[j], sh[j]), 0.f)
                + fmaxf(fmaf(bf2f((unsigned short)v2[j]), sc[j], sh[j]), 0.f)
                + fmaxf(fmaf(bf2f((unsigned short)v3[j]), sc[j], sh[j]), 0.f);
      }
    }
    for (; u < cnt; ++u) {
      int s0 = __shfl(myi, u, 32);
      bf16x8 v0 = *(const bf16x8*)(hb + (size_t)s0 * HIDDIM + off);
#pragma unroll
      for (int j = 0; j < 8; ++j)
        acc[j] += fmaxf(fmaf(bf2f((unsigned short)v0[j]), sc[j], sh[j]), 0.f);
    }
  }

  bf16x8 vd = *(const bf16x8*)(hb + (size_t)d * HIDDIM + off);
  f32x4 xa = __builtin_nontemporal_load((const f32x4*)(x0 + (size_t)d * HIDDIM + off));
  f32x4 xb = __builtin_nontemporal_load((const f32x4*)(x0 + (size_t)d * HIDDIM + off + 4));
  float xs[8] = {xa.x, xa.y, xa.z, xa.w, xb.x, xb.y, xb.z, xb.w};
  bf16x8 o;
#pragma unroll
  for (int j = 0; j < 8; ++j) {
    float hv = fmaxf(fmaf(bf2f((unsigned short)vd[j]), sc[j], sh[j]), 0.f);
    o[j] = (short)f2bf((1.f - kAlpha) * (hv + acc[j]) + kAlpha * xs[j]);
  }
  __builtin_nontemporal_store(o, (bf16x8*)(supp_bf + (size_t)d * HIDDIM + off));
}

// ---------------------------------------------------------------------------
extern "C" void kernel_launch(void* const* d_in, const int* in_sizes, int n_in,
                              void* d_out, int out_size, void* d_ws, size_t ws_size,
                              hipStream_t stream) {
  // inputs: s0, s1, x_0, W_pre, gamma, beta_bn, W_op, edge_index, drop_prob, training
  const float* s1    = (const float*)d_in[1];
  const float* x0    = (const float*)d_in[2];
  const float* W_pre = (const float*)d_in[3];
  const float* gamma = (const float*)d_in[4];
  const float* betab = (const float*)d_in[5];
  const float* W_op  = (const float*)d_in[6];
  const int*   ei    = (const int*)d_in[7];
  float* out = (float*)d_out;

  const size_t NH = (size_t)NNODES * HIDDIM;            // 12.8M elements
  unsigned short* hbf   = (unsigned short*)d_ws;        // 25.6 MB (raw bf16 h)
  unsigned short* supbf = hbf + NH;                     // 25.6 MB
  float* colsum   = (float*)(supbf + NH);               // 256
  float* colsumsq = colsum + HIDDIM;
  unsigned short* wpre_t = (unsigned short*)(colsumsq + HIDDIM);  // 128 KB
  unsigned short* wop_t  = wpre_t + 65536;              // 128 KB
  int* deg      = (int*)(wop_t + 65536);                // 50000
  int* cursor   = deg + NNODES;                         // 50000
  int* rowptr   = cursor + NNODES;                      // 50001
  int* esrc     = rowptr + (NNODES + 1);                // 800000
  int* blocksum = esrc + NEDGES;                        // 256
  int* blockoff = blocksum + 256;                       // 256

  // weights + BN-stat zero + deg zero
  prep_k<<<512, 256, 0, stream>>>(W_pre, W_op, wpre_t, wop_t, colsum, colsumsq, deg);

  // CSR build (round-10 proven 3-dispatch scan)
  hist_k<<<784, 256, 0, stream>>>(ei, deg);
  scanA_k<<<NB_SCAN, 256, 0, stream>>>(deg, rowptr, blocksum);
  scanB_k<<<1, 256, 0, stream>>>(blocksum, blockoff, rowptr);
  scanC_k<<<NB_SCAN, 256, 0, stream>>>(rowptr, blockoff, cursor);
  fill_k<<<1024, 256, 0, stream>>>(ei, cursor, esrc);

  // GEMM1 (persistent, B-in-LDS): fp32 A -> raw bf16 h + BN stats
  gemm_persist_k<0><<<GEMMB, 512, 0, stream>>>(s1, wpre_t, hbf, colsum, colsumsq, NNODES);

  // gather + fused BN-finalize/BN/ReLU + support mix
  agg_bn_support_k<<<(NNODES + 7) / 8, 256, 0, stream>>>(hbf, rowptr, esrc, x0,
                                                         colsum, colsumsq, gamma, betab,
                                                         supbf);

  // GEMM2 (persistent): supp @ W_op + GCNII epilogue (S read from LDS)
  gemm_persist_k<1><<<GEMMB, 512, 0, stream>>>(supbf, wop_t, out, nullptr, nullptr, NNODES);
}

// Round 14
// 218.156 us; speedup vs baseline: 1.0938x; 1.0026x over previous
//
#include <hip/hip_runtime.h>

#define NNODES 50000
#define NEDGES 800000
#define HIDDIM 256
#define NB_SCAN 196   // ceil(NNODES/256)
#define NCHUNK  1563  // ceil(NNODES/32)
#define GEMMB   256   // persistent GEMM blocks (1 per CU)

constexpr float kAlpha = 0.1f;
constexpr float kBnEps = 1e-5f;
constexpr float kBeta  = 0.40546510810816438198f;   // log(1.5)

typedef __attribute__((ext_vector_type(8))) short  bf16x8;   // 8 bf16 in 4 VGPRs
typedef __attribute__((ext_vector_type(4))) float  f32x4;

typedef __attribute__((address_space(1))) const unsigned int gu32;  // global
typedef __attribute__((address_space(3))) unsigned int       lu32;  // LDS

static __device__ __forceinline__ unsigned short f2bf(float f) {
  unsigned u = __float_as_uint(f);
  u = (u + 0x7FFFu + ((u >> 16) & 1u)) >> 16;      // RTNE
  return (unsigned short)u;
}
static __device__ __forceinline__ float bf2f(unsigned short h) {
  return __uint_as_float(((unsigned)h) << 16);
}

// ---------------------------------------------------------------------------
// prep: weight transposes (fp32 [k][n] -> bf16 [n][k]) + zero BN stats + deg
// ---------------------------------------------------------------------------
__global__ __launch_bounds__(256) void prep_k(const float* __restrict__ W_pre,
                                              const float* __restrict__ W_op,
                                              unsigned short* __restrict__ wpre_t,
                                              unsigned short* __restrict__ wop_t,
                                              float* __restrict__ colsum,
                                              float* __restrict__ colsumsq,
                                              int* __restrict__ deg) {
  int b = blockIdx.x, t = threadIdx.x;
  if (b < 256) {
    wpre_t[b * 256 + t] = f2bf(W_pre[t * 256 + b]);
    if (b == 0) { colsum[t] = 0.f; colsumsq[t] = 0.f; }
  } else {
    int n = b - 256;
    wop_t[n * 256 + t] = f2bf(W_op[t * 256 + n]);
  }
  if (b < NB_SCAN) {
    int idx = b * 256 + t;
    if (idx < NNODES) deg[idx] = 0;
  }
}

// ---------------------------------------------------------------------------
// CSR build: degree histogram -> 3-phase parallel scan -> bucket src ids
// (round-10 proven versions)
// ---------------------------------------------------------------------------
__global__ __launch_bounds__(256) void hist_k(const int* __restrict__ ei,
                                              int* __restrict__ deg) {
  const int4* dst4 = (const int4*)(ei + NEDGES);
  const int n4 = NEDGES / 4;
  int stride = gridDim.x * blockDim.x;
  for (int i = blockIdx.x * blockDim.x + threadIdx.x; i < n4; i += stride) {
    int4 d = dst4[i];
    atomicAdd(&deg[d.x], 1);
    atomicAdd(&deg[d.y], 1);
    atomicAdd(&deg[d.z], 1);
    atomicAdd(&deg[d.w], 1);
  }
}

__global__ __launch_bounds__(256) void scanA_k(const int* __restrict__ deg,
                                               int* __restrict__ rowptr,
                                               int* __restrict__ blocksum) {
  __shared__ int sh[256];
  const int t = threadIdx.x;
  const int idx = blockIdx.x * 256 + t;
  int v = (idx < NNODES) ? deg[idx] : 0;
  sh[t] = v;
  __syncthreads();
  for (int off = 1; off < 256; off <<= 1) {
    int x = (t >= off) ? sh[t - off] : 0;
    __syncthreads();
    sh[t] += x;
    __syncthreads();
  }
  if (idx < NNODES) rowptr[idx] = sh[t] - v;      // exclusive within block
  if (t == 255) blocksum[blockIdx.x] = sh[255];
}

__global__ __launch_bounds__(256) void scanB_k(const int* __restrict__ blocksum,
                                               int* __restrict__ blockoff,
                                               int* __restrict__ rowptr) {
  __shared__ int sh[256];
  const int t = threadIdx.x;
  int v = (t < NB_SCAN) ? blocksum[t] : 0;
  sh[t] = v;
  __syncthreads();
  for (int off = 1; off < 256; off <<= 1) {
    int x = (t >= off) ? sh[t - off] : 0;
    __syncthreads();
    sh[t] += x;
    __syncthreads();
  }
  blockoff[t] = sh[t] - v;                        // exclusive block offset
  if (t == 255) rowptr[NNODES] = sh[255];         // grand total (=NEDGES)
}

__global__ __launch_bounds__(256) void scanC_k(int* __restrict__ rowptr,
                                               const int* __restrict__ blockoff,
                                               int* __restrict__ cursor) {
  const int idx = blockIdx.x * 256 + threadIdx.x;
  if (idx < NNODES) {
    int rp = rowptr[idx] + blockoff[blockIdx.x];
    rowptr[idx] = rp;
    cursor[idx] = rp;
  }
}

__global__ __launch_bounds__(256) void fill_k(const int* __restrict__ ei,
                                              int* __restrict__ cursor,
                                              int* __restrict__ esrc) {
  const int4* src4 = (const int4*)ei;
  const int4* dst4 = (const int4*)(ei + NEDGES);
  const int n4 = NEDGES / 4;
  int stride = gridDim.x * blockDim.x;
  for (int i = blockIdx.x * blockDim.x + threadIdx.x; i < n4; i += stride) {
    int4 s = src4[i];
    int4 d = dst4[i];
    esrc[atomicAdd(&cursor[d.x], 1)] = s.x;
    esrc[atomicAdd(&cursor[d.y], 1)] = s.y;
    esrc[atomicAdd(&cursor[d.z], 1)] = s.z;
    esrc[atomicAdd(&cursor[d.w], 1)] = s.w;
  }
}

// ---------------------------------------------------------------------------
// PERSISTENT bf16 MFMA GEMM: C = A[M,256] @ B[256,256], Bt transposed [n][k].
// 256 blocks (1/CU), 512 threads (8 waves as 2 row-groups x 4 col-groups).
// B (128 KB) lives in LDS for the whole kernel; A streams through a 2x16KB
// double buffer in 32-row chunks; one barrier per chunk; full K=256 per MFMA
// pass (32 MFMA/wave/chunk). XOR swizzle ((row&7)<<4) on 512-B LDS rows;
// global_load_lds sources are inverse-swizzled (rule #21).
// MODE 0: A fp32 (reg-staged+converted); C bf16 + col stats (reg-accumulated,
//         one atomicAdd/col/block at end).
// MODE 1: A bf16 via global_load_lds; S residual == A read back from LDS;
//         C fp32 = relu((1-beta)*S + beta*(A@B)).
// ---------------------------------------------------------------------------
template<int MODE>
__global__ __launch_bounds__(512) void gemm_persist_k(
    const void* __restrict__ Ain,
    const unsigned short* __restrict__ Bt,   // [256][256] bf16, Bt[n][k]
    void* __restrict__ Cout,                 // MODE0: bf16; MODE1: float
    float* __restrict__ colsum,
    float* __restrict__ colsumsq,
    int M) {
  __shared__ __align__(16) unsigned short Bl[256 * 256];   // 128 KB, 512 B rows
  __shared__ __align__(16) unsigned short Al[2][32 * 256]; // 2 x 16 KB

  const int t    = threadIdx.x;          // 0..511
  const int lane = t & 63;
  const int wid  = t >> 6;               // 0..7
  const int wr   = wid >> 2;             // row group 0/1 (16 rows each)
  const int wc   = wid & 3;              // col group 0..3 (64 cols each)

  // ---- B preload: 128 issues x 1 KB (2 rows each), 16 per wave ----
  {
    const int lrow = lane >> 5;          // 0..1
    const int lchk = lane & 31;          // 16B chunk in 512-B row
#pragma unroll
    for (int c = 0; c < 16; ++c) {
      int issue = wid * 16 + c;          // 0..127
      int row = issue * 2 + lrow;        // 0..255
      int srcoff = (lchk * 16) ^ ((row & 7) << 4);
      const char* g = (const char*)Bt + (size_t)row * 512 + srcoff;
      char* l = (char*)Bl + issue * 1024 + lane * 16;
      __builtin_amdgcn_global_load_lds((gu32*)g, (lu32*)l, 16, 0, 0);
    }
  }

  float spart[4] = {0.f, 0.f, 0.f, 0.f};
  float qpart[4] = {0.f, 0.f, 0.f, 0.f};

  auto stageA = [&](int buf, int chunk) {
    const int r0 = chunk * 32;
    if (MODE == 0) {
      // 512 threads -> (row 0..31, seg 0..15 of 16 fp32)
      const int row = t >> 4;
      const int seg = t & 15;
      const int arow = r0 + row;
      const float* src = (const float*)Ain + (size_t)arow * 256 + seg * 16;
      bf16x8 v0 = {}, v1 = {};
      if (arow < M) {
        float4 p0 = *(const float4*)(src + 0);
        float4 p1 = *(const float4*)(src + 4);
        float4 p2 = *(const float4*)(src + 8);
        float4 p3 = *(const float4*)(src + 12);
        v0[0] = (short)f2bf(p0.x); v0[1] = (short)f2bf(p0.y);
        v0[2] = (short)f2bf(p0.z); v0[3] = (short)f2bf(p0.w);
        v0[4] = (short)f2bf(p1.x); v0[5] = (short)f2bf(p1.y);
        v0[6] = (short)f2bf(p1.z); v0[7] = (short)f2bf(p1.w);
        v1[0] = (short)f2bf(p2.x); v1[1] = (short)f2bf(p2.y);
        v1[2] = (short)f2bf(p2.z); v1[3] = (short)f2bf(p2.w);
        v1[4] = (short)f2bf(p3.x); v1[5] = (short)f2bf(p3.y);
        v1[6] = (short)f2bf(p3.z); v1[7] = (short)f2bf(p3.w);
      }
      char* base = (char*)&Al[buf][0] + row * 512;
      const int sw = (row & 7) << 4;
      *(bf16x8*)(base + ((seg * 32 +  0) ^ sw)) = v0;
      *(bf16x8*)(base + ((seg * 32 + 16) ^ sw)) = v1;
    } else {
      // 16 issues x 1 KB (2 rows each), 2 per wave
      const int lrow = lane >> 5;
      const int lchk = lane & 31;
#pragma unroll
      for (int c = 0; c < 2; ++c) {
        int issue = wid * 2 + c;         // 0..15
        int row = issue * 2 + lrow;      // 0..31
        int srcoff = (lchk * 16) ^ ((row & 7) << 4);
        const char* g = (const char*)Ain + (size_t)(r0 + row) * 512 + srcoff;
        char* l = (char*)&Al[buf][0] + issue * 1024 + lane * 16;
        __builtin_amdgcn_global_load_lds((gu32*)g, (lu32*)l, 16, 0, 0);
      }
    }
  };

  stageA(0, blockIdx.x);
  __syncthreads();                       // B + first A ready

  int nc = 0;
  for (int c = blockIdx.x; c < NCHUNK; c += GEMMB, ++nc) {
    const int cur = nc & 1;
    const int cn = c + GEMMB;
    if (cn < NCHUNK) stageA(cur ^ 1, cn);   // next chunk flies under MFMA

    // ---- compute: full K=256, 8 k-slices x 4 n = 32 MFMA ----
    f32x4 acc[4] = {};
    const int arow_f = wr * 16 + (lane & 15);
    const int asw = (arow_f & 7) << 4;
#pragma unroll
    for (int ks = 0; ks < 8; ++ks) {
      const int koff = ks * 64 + ((lane >> 4) * 16);
      bf16x8 af = *(const bf16x8*)((char*)&Al[cur][0] + arow_f * 512 + (koff ^ asw));
#pragma unroll
      for (int n = 0; n < 4; ++n) {
        int nr = wc * 64 + n * 16 + (lane & 15);
        bf16x8 bfr = *(const bf16x8*)((char*)Bl + (size_t)nr * 512 + (koff ^ ((nr & 7) << 4)));
        acc[n] = __builtin_amdgcn_mfma_f32_16x16x32_bf16(af, bfr, acc[n], 0, 0, 0);
      }
    }

    // ---- epilogue (C/D layout: col=lane&15, row=(lane>>4)*4+r) ----
    if (MODE == 0) {
      unsigned short* hC = (unsigned short*)Cout;
#pragma unroll
      for (int n = 0; n < 4; ++n) {
        int col = wc * 64 + n * 16 + (lane & 15);
        float s = 0.f, q = 0.f;
#pragma unroll
        for (int r = 0; r < 4; ++r) {
          int row = c * 32 + wr * 16 + (lane >> 4) * 4 + r;
          float v = acc[n][r];
          s += v; q += v * v;
          if (row < M) hC[(size_t)row * 256 + col] = f2bf(v);
        }
        spart[n] += s; qpart[n] += q;
      }
    } else {
      float* oC = (float*)Cout;
#pragma unroll
      for (int n = 0; n < 4; ++n) {
        int col = wc * 64 + n * 16 + (lane & 15);
#pragma unroll
        for (int r = 0; r < 4; ++r) {
          int rl = wr * 16 + (lane >> 4) * 4 + r;
          int row = c * 32 + rl;
          if (row < M) {
            // residual S == A row, still resident in Al[cur]
            unsigned short sv = *(const unsigned short*)
                ((char*)&Al[cur][0] + rl * 512 + ((col * 2) ^ ((rl & 7) << 4)));
            oC[(size_t)row * 256 + col] =
                fmaxf((1.f - kBeta) * bf2f(sv) + kBeta * acc[n][r], 0.f);
          }
        }
      }
    }
    __syncthreads();   // drains next-chunk loads; protects Al[cur] for rewrite
  }

  // ---- MODE 0: fold register col-stats into global (1 atomic/col/block) ----
  if (MODE == 0) {
#pragma unroll
    for (int n = 0; n < 4; ++n) {
      float s = spart[n], q = qpart[n];
      s += __shfl_xor(s, 16); s += __shfl_xor(s, 32);
      q += __shfl_xor(q, 16); q += __shfl_xor(q, 32);
      if (lane < 16) {
        int col = wc * 64 + n * 16 + lane;
        atomicAdd(&colsum[col], s);
        atomicAdd(&colsumsq[col], q);
      }
    }
  }
}

// ---------------------------------------------------------------------------
// Gather-sum per destination node with fused BN-finalize + BN/ReLU + GCNII
// support mix (round-10 proven version).
// ---------------------------------------------------------------------------
__global__ __launch_bounds__(256) void agg_bn_support_k(
    const unsigned short* __restrict__ hb,
    const int* __restrict__ rowptr,
    const int* __restrict__ esrc,
    const float* __restrict__ x0,
    const float* __restrict__ colsum,
    const float* __restrict__ colsumsq,
    const float* __restrict__ gamma,
    const float* __restrict__ beta_bn,
    unsigned short* __restrict__ supp_bf) {
  __shared__ float s_sc[256], s_sh[256];
  {
    int j = threadIdx.x;
    float inv_n = 1.0f / (float)NNODES;
    float mu  = colsum[j] * inv_n;
    float var = colsumsq[j] * inv_n - mu * mu;
    float rstd = rsqrtf(var + kBnEps);
    float g = gamma[j] * rstd;
    s_sc[j] = g;
    s_sh[j] = beta_bn[j] - mu * g;
  }
  __syncthreads();

  const int hw   = threadIdx.x >> 5;
  const int lane = threadIdx.x & 31;
  const int d    = blockIdx.x * 8 + hw;
  const int off  = lane * 8;

  float sc[8], sh[8];
  *(float4*)&sc[0] = *(const float4*)(s_sc + off);
  *(float4*)&sc[4] = *(const float4*)(s_sc + off + 4);
  *(float4*)&sh[0] = *(const float4*)(s_sh + off);
  *(float4*)&sh[4] = *(const float4*)(s_sh + off + 4);

  const int beg = rowptr[d];
  const int end = rowptr[d + 1];
  float acc[8] = {0.f, 0.f, 0.f, 0.f, 0.f, 0.f, 0.f, 0.f};

  for (int bb = beg; bb < end; bb += 32) {
    int cnt = end - bb; if (cnt > 32) cnt = 32;
    int myi = esrc[bb + ((lane < cnt) ? lane : 0)];
    int u = 0;
    for (; u + 3 < cnt; u += 4) {
      int s0 = __shfl(myi, u, 32),     s1 = __shfl(myi, u + 1, 32);
      int s2 = __shfl(myi, u + 2, 32), s3 = __shfl(myi, u + 3, 32);
      bf16x8 v0 = *(const bf16x8*)(hb + (size_t)s0 * HIDDIM + off);
      bf16x8 v1 = *(const bf16x8*)(hb + (size_t)s1 * HIDDIM + off);
      bf16x8 v2 = *(const bf16x8*)(hb + (size_t)s2 * HIDDIM + off);
      bf16x8 v3 = *(const bf16x8*)(hb + (size_t)s3 * HIDDIM + off);
#pragma unroll
      for (int j = 0; j < 8; ++j) {
        acc[j] += fmaxf(fmaf(bf2f((unsigned short)v0[j]), sc[j], sh[j]), 0.f)
                + fmaxf(fmaf(bf2f((unsigned short)v1[j]), sc[j], sh[j]), 0.f)
                + fmaxf(fmaf(bf2f((unsigned short)v2[j]), sc[j], sh[j]), 0.f)
                + fmaxf(fmaf(bf2f((unsigned short)v3[j]), sc[j], sh[j]), 0.f);
      }
    }
    for (; u < cnt; ++u) {
      int s0 = __shfl(myi, u, 32);
      bf16x8 v0 = *(const bf16x8*)(hb + (size_t)s0 * HIDDIM + off);
#pragma unroll
      for (int j = 0; j < 8; ++j)
        acc[j] += fmaxf(fmaf(bf2f((unsigned short)v0[j]), sc[j], sh[j]), 0.f);
    }
  }

  bf16x8 vd = *(const bf16x8*)(hb + (size_t)d * HIDDIM + off);
  f32x4 xa = __builtin_nontemporal_load((const f32x4*)(x0 + (size_t)d * HIDDIM + off));
  f32x4 xb = __builtin_nontemporal_load((const f32x4*)(x0 + (size_t)d * HIDDIM + off + 4));
  float xs[8] = {xa.x, xa.y, xa.z, xa.w, xb.x, xb.y, xb.z, xb.w};
  bf16x8 o;
#pragma unroll
  for (int j = 0; j < 8; ++j) {
    float hv = fmaxf(fmaf(bf2f((unsigned short)vd[j]), sc[j], sh[j]), 0.f);
    o[j] = (short)f2bf((1.f - kAlpha) * (hv + acc[j]) + kAlpha * xs[j]);
  }
  __builtin_nontemporal_store(o, (bf16x8*)(supp_bf + (size_t)d * HIDDIM + off));
}

// ---------------------------------------------------------------------------
extern "C" void kernel_launch(void* const* d_in, const int* in_sizes, int n_in,
                              void* d_out, int out_size, void* d_ws, size_t ws_size,
                              hipStream_t stream) {
  // inputs: s0, s1, x_0, W_pre, gamma, beta_bn, W_op, edge_index, drop_prob, training
  const float* s1    = (const float*)d_in[1];
  const float* x0    = (const float*)d_in[2];
  const float* W_pre = (const float*)d_in[3];
  const float* gamma = (const float*)d_in[4];
  const float* betab = (const float*)d_in[5];
  const float* W_op  = (const float*)d_in[6];
  const int*   ei    = (const int*)d_in[7];
  float* out = (float*)d_out;

  const size_t NH = (size_t)NNODES * HIDDIM;            // 12.8M elements
  unsigned short* hbf   = (unsigned short*)d_ws;        // 25.6 MB (raw bf16 h)
  unsigned short* supbf = hbf + NH;                     // 25.6 MB
  float* colsum   = (float*)(supbf + NH);               // 256
  float* colsumsq = colsum + HIDDIM;
  unsigned short* wpre_t = (unsigned short*)(colsumsq + HIDDIM);  // 128 KB
  unsigned short* wop_t  = wpre_t + 65536;              // 128 KB
  int* deg      = (int*)(wop_t + 65536);                // 50000
  int* cursor   = deg + NNODES;                         // 50000
  int* rowptr   = cursor + NNODES;                      // 50001
  int* esrc     = rowptr + (NNODES + 1);                // 800000
  int* blocksum = esrc + NEDGES;                        // 256
  int* blockoff = blocksum + 256;                       // 256

  // weights + BN-stat zero + deg zero
  prep_k<<<512, 256, 0, stream>>>(W_pre, W_op, wpre_t, wop_t, colsum, colsumsq, deg);

  // CSR build (round-10 proven 3-dispatch scan)
  hist_k<<<784, 256, 0, stream>>>(ei, deg);
  scanA_k<<<NB_SCAN, 256, 0, stream>>>(deg, rowptr, blocksum);
  scanB_k<<<1, 256, 0, stream>>>(blocksum, blockoff, rowptr);
  scanC_k<<<NB_SCAN, 256, 0, stream>>>(rowptr, blockoff, cursor);
  fill_k<<<1024, 256, 0, stream>>>(ei, cursor, esrc);

  // GEMM1 (persistent, B-in-LDS): fp32 A -> raw bf16 h + BN stats
  gemm_persist_k<0><<<GEMMB, 512, 0, stream>>>(s1, wpre_t, hbf, colsum, colsumsq, NNODES);

  // gather + fused BN-finalize/BN/ReLU + support mix
  agg_bn_support_k<<<(NNODES + 7) / 8, 256, 0, stream>>>(hbf, rowptr, esrc, x0,
                                                         colsum, colsumsq, gamma, betab,
                                                         supbf);

  // GEMM2 (persistent): supp @ W_op + GCNII epilogue (S read from LDS)
  gemm_persist_k<1><<<GEMMB, 512, 0, stream>>>(supbf, wop_t, out, nullptr, nullptr, NNODES);
}